// Round 1
// 1470.048 us; speedup vs baseline: 1.2468x; 1.2468x over previous
//
#include <hip/hip_runtime.h>
#include <math.h>
#include <stdint.h>

typedef float f32x4 __attribute__((ext_vector_type(4)));
typedef short short8 __attribute__((ext_vector_type(8)));

static constexpr int HWo   = 3136;   // 56*56
static constexpr int NB    = 8;
static constexpr int NP    = 3200;   // padded pixel / centroid count (25*128)
static constexpr int KDIM  = 1794;   // 1792 + 2 coord channels
static constexpr int KP1   = 1856;   // gemm1 K padded to 29*64
static constexpr int ODIM  = 1792;   // gemm2 K = 28*64
static constexpr int NCENT = 3136;

__device__ __forceinline__ uint16_t f2bf(float f) {
  union { float f; uint32_t u; } v; v.f = f;
  uint32_t u = v.u;
  return (uint16_t)((u + 0x7FFFu + ((u >> 16) & 1u)) >> 16);   // RNE
}
__device__ __forceinline__ float bf2f(uint16_t h) {
  union { uint32_t u; float f; } v; v.u = ((uint32_t)h) << 16;
  return v.f;
}

// async global->LDS, 16B per lane; LDS dest is wave-uniform base + lane*16
__device__ __forceinline__ void gld16(const uint16_t* __restrict__ g, uint16_t* l) {
  __builtin_amdgcn_global_load_lds(
      (const __attribute__((address_space(1))) uint16_t*)g,
      (__attribute__((address_space(3))) uint16_t*)l,
      16, 0, 0);
}

// ---------------- one-time converts ----------------
__global__ __launch_bounds__(256) void convW_kernel(const float* __restrict__ W, uint16_t* __restrict__ Wh) {
  int idx = blockIdx.x * 256 + threadIdx.x;          // 1792*1856 exact
  int o = idx / KP1, k = idx % KP1;
  float v = (k < KDIM) ? W[(size_t)o * KDIM + k] : 0.f;
  Wh[idx] = f2bf(v);
}

__global__ __launch_bounds__(256) void convC_kernel(const float* __restrict__ C, uint16_t* __restrict__ Ct) {
  int idx = blockIdx.x * 256 + threadIdx.x;          // 3136*1792 exact
  int j = idx / ODIM, o = idx % ODIM;
  Ct[(size_t)j * ODIM + o] = f2bf(C[(size_t)o * NCENT + j]);
}

// ---------------- row squared-norms of a bf16 [*][1792] matrix ----------------
__global__ __launch_bounds__(256) void rownorm_kernel(const uint16_t* __restrict__ src, float* __restrict__ dst) {
  int t = threadIdx.x, lane = t & 63, wave = t >> 6;
  int row = blockIdx.x * 4 + wave;
  const uint32_t* p = (const uint32_t*)(src + (size_t)row * ODIM);
  float s = 0.f;
  #pragma unroll
  for (int it = 0; it < 14; ++it) {                  // 896 uint pairs / 64 lanes
    uint32_t u = p[it * 64 + lane];
    float a = bf2f((uint16_t)(u & 0xFFFF)), b = bf2f((uint16_t)(u >> 16));
    s += a * a + b * b;
  }
  #pragma unroll
  for (int m = 1; m < 64; m <<= 1) s += __shfl_xor(s, m, 64);
  if (lane == 0) dst[row] = s;
}

// ---------------- pooling (all 3 levels, native res, fp32), batched on blockIdx.y ----------------
static constexpr int P1SZ = 256 * 3136;   // 802816
static constexpr int P2SZ = 512 * 784;    // 401408
static constexpr int P3SZ = 1024 * 196;   // 200704
static constexpr int PTOT = P1SZ + P2SZ + P3SZ;      // 1404928

__device__ __forceinline__ float pool9f(const float* __restrict__ p, int S, int y, int x) {
  float s = 0.f;
  for (int dy = -1; dy <= 1; ++dy) {
    int yy = y + dy; if (yy < 0 || yy >= S) continue;
    for (int dx = -1; dx <= 1; ++dx) {
      int xx = x + dx; if (xx < 0 || xx >= S) continue;
      s += p[yy * S + xx];
    }
  }
  return s * (1.f / 9.f);
}

__global__ __launch_bounds__(256) void pool_kernel(const float* __restrict__ p1, const float* __restrict__ p2,
                                                   const float* __restrict__ p3, float* __restrict__ pooled, int g0) {
  int b = g0 + blockIdx.y;
  float* pb = pooled + (size_t)blockIdx.y * PTOT;
  int idx = blockIdx.x * 256 + threadIdx.x;          // PTOT exact
  const float* src; int S, loc;
  if (idx < P1SZ)              { src = p1 + (size_t)b * P1SZ; S = 56; loc = idx; }
  else if (idx < P1SZ + P2SZ)  { src = p2 + (size_t)b * P2SZ; S = 28; loc = idx - P1SZ; }
  else                         { src = p3 + (size_t)b * P3SZ; S = 14; loc = idx - P1SZ - P2SZ; }
  int c = loc / (S * S), hw = loc % (S * S);
  pb[idx] = pool9f(src + (size_t)c * S * S, S, hw / S, hw % S);
}

// ---------------- assemble xcb bf16 [bg*3200 + 3136][1856] pixel-major ----------------
__global__ __launch_bounds__(256) void assemble_kernel(const float* __restrict__ pooled, uint16_t* __restrict__ xcb) {
  int bg = blockIdx.y;
  const float* pb = pooled + (size_t)bg * PTOT;
  uint16_t* xb = xcb + (size_t)bg * NP * KP1;
  int idx = blockIdx.x * 256 + threadIdx.x;          // 3136*1856 exact
  int i = idx / KP1, ch = idx % KP1;
  int x = i % 56, y = i / 56;
  float v;
  if (ch < 256) {
    v = pb[ch * 3136 + i];
  } else if (ch < 1792) {
    const float* base; int S; float scale, shift;
    if (ch < 768) { base = pb + P1SZ + (ch - 256) * 784;          S = 28; scale = 0.5f;  shift = -0.25f;  }
    else          { base = pb + P1SZ + P2SZ + (ch - 768) * 196;   S = 14; scale = 0.25f; shift = -0.375f; }
    float sx = x * scale + shift, sy = y * scale + shift;
    float fx0 = floorf(sx), fy0 = floorf(sy);
    float fx = sx - fx0, fy = sy - fy0;
    int x0 = (int)fx0, y0 = (int)fy0, x1 = x0 + 1, y1 = y0 + 1;
    x0 = x0 < 0 ? 0 : x0; x1 = x1 > S - 1 ? S - 1 : x1;
    y0 = y0 < 0 ? 0 : y0; y1 = y1 > S - 1 ? S - 1 : y1;
    float v00 = base[y0 * S + x0], v01 = base[y0 * S + x1];
    float v10 = base[y1 * S + x0], v11 = base[y1 * S + x1];
    v = (1.f - fy) * ((1.f - fx) * v00 + fx * v01) + fy * ((1.f - fx) * v10 + fx * v11);
  } else if (ch == 1792) v = -1.f + 2.f * x / 55.f;
  else if (ch == 1793)   v = -1.f + 2.f * y / 55.f;
  else                   v = 0.f;                    // K padding: MUST be zero
  xb[idx] = f2bf(v);
}

// ---------------- MFMA GEMM1 (m97 recipe): phi_t[i][o] = sum_k W[o][k]*xc[i][k] + bias[o] ----------------
// A = Wh [1792][1856] (m=o), B = xcb [GB*3200][1856] (n=i global). Linear LDS + global_load_lds(16).
__global__ __launch_bounds__(256) void gemm1_mfma(const uint16_t* __restrict__ Wh, const float* __restrict__ bias,
                                                  const uint16_t* __restrict__ xcb, uint16_t* __restrict__ phi_t) {
  __shared__ uint16_t As[128][64];   // linear: required by global_load_lds (wave-uniform dst + lane*16)
  __shared__ uint16_t Bs[128][64];
  int t = threadIdx.x;
  int row0 = blockIdx.y * 128;       // o
  int col0 = blockIdx.x * 128;       // i (global pixel incl. group)
  int lane = t & 63, wave = t >> 6;
  int wm = wave & 1, wn = wave >> 1;
  int l15 = lane & 15, quad = lane >> 4;
  int rr = wave * 8 + (lane >> 3);   // staging row within 32-row stripe
  int sg = (lane & 7) * 8;           // staging col (uint16 units), 16B chunks
  f32x4 acc[4][4] = {};
  for (int k0 = 0; k0 < KP1; k0 += 64) {
    #pragma unroll
    for (int i = 0; i < 4; ++i) {
      gld16(&Wh [(size_t)(row0 + i * 32 + rr) * KP1 + k0 + sg], &As[i * 32 + wave * 8][0]);
      gld16(&xcb[(size_t)(col0 + i * 32 + rr) * KP1 + k0 + sg], &Bs[i * 32 + wave * 8][0]);
    }
    __syncthreads();                 // compiler emits vmcnt(0) before s_barrier -> LDS tiles ready
    #pragma unroll
    for (int kk = 0; kk < 2; ++kk) {
      int ko = kk * 32 + quad * 8;
      short8 a[4], b[4];
      #pragma unroll
      for (int i = 0; i < 4; ++i) a[i] = *(const short8*)&As[wm * 64 + i * 16 + l15][ko];
      #pragma unroll
      for (int j = 0; j < 4; ++j) b[j] = *(const short8*)&Bs[wn * 64 + j * 16 + l15][ko];
      #pragma unroll
      for (int i = 0; i < 4; ++i)
        #pragma unroll
        for (int j = 0; j < 4; ++j)
          acc[i][j] = __builtin_amdgcn_mfma_f32_16x16x32_bf16(a[i], b[j], acc[i][j], 0, 0, 0);
    }
    __syncthreads();
  }
  // D: col(lane&15)=i, row(quad*4+reg)=o. Store transposed: phi_t[i][o..o+3] as ushort4.
  #pragma unroll
  for (int i = 0; i < 4; ++i) {
    int ob = row0 + wm * 64 + i * 16 + quad * 4;
    float4 bv = *(const float4*)&bias[ob];
    float bb[4] = {bv.x, bv.y, bv.z, bv.w};
    #pragma unroll
    for (int j = 0; j < 4; ++j) {
      int ic = col0 + wn * 64 + j * 16 + l15;
      ushort4 u;
      u.x = f2bf(acc[i][j][0] + bb[0]);
      u.y = f2bf(acc[i][j][1] + bb[1]);
      u.z = f2bf(acc[i][j][2] + bb[2]);
      u.w = f2bf(acc[i][j][3] + bb[3]);
      *(ushort4*)&phi_t[(size_t)ic * ODIM + ob] = u;
    }
  }
}

// ---------------- MFMA GEMM2 (m97 recipe): key[i][j] = cent[j] - 2*sum_o phi_t[i][o]*Ct[j][o] ----------------
__global__ __launch_bounds__(256) void gemm2_mfma(const uint16_t* __restrict__ phi_t, const uint16_t* __restrict__ Ct,
                                                  const float* __restrict__ cent, uint16_t* __restrict__ key) {
  __shared__ uint16_t As[128][64];
  __shared__ uint16_t Bs[128][64];
  int t = threadIdx.x;
  int row0 = blockIdx.y * 128;       // i (global pixel incl. group)
  int col0 = blockIdx.x * 128;       // j (centroid)
  int lane = t & 63, wave = t >> 6;
  int wm = wave & 1, wn = wave >> 1;
  int l15 = lane & 15, quad = lane >> 4;
  int rr = wave * 8 + (lane >> 3);
  int sg = (lane & 7) * 8;
  f32x4 acc[4][4] = {};
  for (int k0 = 0; k0 < ODIM; k0 += 64) {
    #pragma unroll
    for (int i = 0; i < 4; ++i) {
      gld16(&phi_t[(size_t)(row0 + i * 32 + rr) * ODIM + k0 + sg], &As[i * 32 + wave * 8][0]);
      gld16(&Ct   [(size_t)(col0 + i * 32 + rr) * ODIM + k0 + sg], &Bs[i * 32 + wave * 8][0]);
    }
    __syncthreads();
    #pragma unroll
    for (int kk = 0; kk < 2; ++kk) {
      int ko = kk * 32 + quad * 8;
      short8 a[4], b[4];
      #pragma unroll
      for (int i = 0; i < 4; ++i) a[i] = *(const short8*)&As[wm * 64 + i * 16 + l15][ko];
      #pragma unroll
      for (int j = 0; j < 4; ++j) b[j] = *(const short8*)&Bs[wn * 64 + j * 16 + l15][ko];
      #pragma unroll
      for (int i = 0; i < 4; ++i)
        #pragma unroll
        for (int j = 0; j < 4; ++j)
          acc[i][j] = __builtin_amdgcn_mfma_f32_16x16x32_bf16(a[i], b[j], acc[i][j], 0, 0, 0);
    }
    __syncthreads();
  }
  #pragma unroll
  for (int j = 0; j < 4; ++j) {
    int jc = col0 + wn * 64 + j * 16 + l15;
    float cv = cent[jc < NCENT ? jc : 0];
    #pragma unroll
    for (int i = 0; i < 4; ++i) {
      int ib = row0 + wm * 64 + i * 16 + quad * 4;
      #pragma unroll
      for (int r = 0; r < 4; ++r)
        key[(size_t)(ib + r) * NP + jc] = f2bf(cv - 2.f * acc[i][j][r]);
    }
  }
}

// ---------------- top-3 + softmin score, one wave per valid row, batched ----------------
__device__ __forceinline__ void ins3(float v, float& a, float& b, float& c) {
  if (v < c) {
    if (v < b) { c = b; if (v < a) { b = a; a = v; } else { b = v; } }
    else { c = v; }
  }
}

__global__ __launch_bounds__(256) void topk_kernel(const uint16_t* __restrict__ key, const float* __restrict__ feat,
                                                   float* __restrict__ out, int g0) {
  int t = threadIdx.x, lane = t & 63, wave = t >> 6;
  int gi = blockIdx.x * 4 + wave;                    // [0, GB*3136)
  int bg = gi / HWo, row = gi - bg * HWo;
  int grow = bg * NP + row;                          // row in key/feat (padded per batch)
  const uint32_t* p = (const uint32_t*)(key + (size_t)grow * NP);
  float t0 = 3.4e38f, t1 = 3.4e38f, t2 = 3.4e38f;
  for (int it = 0; it < 25; ++it) {                  // 1568 pairs, last iter partial
    int q = it * 64 + lane;
    if (q < 1568) {
      uint32_t u = p[q];
      ins3(bf2f((uint16_t)(u & 0xFFFF)), t0, t1, t2);
      ins3(bf2f((uint16_t)(u >> 16)), t0, t1, t2);
    }
  }
  #pragma unroll
  for (int m = 1; m < 64; m <<= 1) {
    float u0 = __shfl_xor(t0, m, 64);
    float u1 = __shfl_xor(t1, m, 64);
    float u2 = __shfl_xor(t2, m, 64);
    ins3(u0, t0, t1, t2); ins3(u1, t0, t1, t2); ins3(u2, t0, t1, t2);
  }
  if (lane == 0) {
    float ft = feat[grow];
    float v0 = sqrtf(fmaxf(ft + t0, 0.f));
    float v1 = sqrtf(fmaxf(ft + t1, 0.f));
    float v2 = sqrtf(fmaxf(ft + t2, 0.f));
    float w0 = 1.f / (1.f + expf(v0 - v1) + expf(v0 - v2));
    out[(size_t)(g0 + bg) * HWo + row] = v0 * w0;
  }
}

// ---------------- launch ----------------
extern "C" void kernel_launch(void* const* d_in, const int* in_sizes, int n_in,
                              void* d_out, int out_size, void* d_ws, size_t ws_size,
                              hipStream_t stream) {
  const float* p1   = (const float*)d_in[0];
  const float* p2   = (const float*)d_in[1];
  const float* p3   = (const float*)d_in[2];
  const float* Wm   = (const float*)d_in[3];
  const float* bias = (const float*)d_in[4];
  const float* Cm   = (const float*)d_in[5];
  float* out = (float*)d_out;

  // adaptive group size: batch as many images per launch group as the workspace allows
  const size_t szWh   = (size_t)ODIM * KP1 * 2;       // 6,651,904
  const size_t szCt   = (size_t)NP * ODIM * 2;        // 11,468,800
  const size_t szCent = 3200 * 4;
  const size_t szFeat = (size_t)NP * 4;               // per group-batch
  const size_t szPool = (size_t)PTOT * 4;             // per group-batch
  const size_t szXcb  = (size_t)NP * KP1 * 2;         // per group-batch
  const size_t szPhi  = (size_t)NP * ODIM * 2;        // per group-batch
  const size_t szKey  = (size_t)NP * NP * 2;          // per group-batch
  const size_t fixedSz = szWh + szCt + szCent;
  const size_t perSz   = szFeat + szPool + szXcb + szPhi + szKey;   // 49,459,712
  int GB = 8;
  while (GB > 1 && fixedSz + perSz * (size_t)GB > ws_size) GB >>= 1;

  char* ws = (char*)d_ws;
  size_t off = 0;
  uint16_t* Wh     = (uint16_t*)(ws + off); off += szWh;
  uint16_t* Ct     = (uint16_t*)(ws + off); off += szCt;
  float*    cent   = (float*)(ws + off);    off += szCent;
  float*    feat   = (float*)(ws + off);    off += szFeat * GB;
  float*    pooled = (float*)(ws + off);    off += szPool * GB;
  uint16_t* xcb    = (uint16_t*)(ws + off); off += szXcb * GB;
  uint16_t* phi_t  = (uint16_t*)(ws + off); off += szPhi * GB;
  uint16_t* key    = (uint16_t*)(ws + off); off += szKey * GB;

  convW_kernel<<<(ODIM * KP1) / 256, 256, 0, stream>>>(Wm, Wh);
  convC_kernel<<<(NCENT * ODIM) / 256, 256, 0, stream>>>(Cm, Ct);
  rownorm_kernel<<<784, 256, 0, stream>>>(Ct, cent);

  for (int g0 = 0; g0 < NB; g0 += GB) {
    pool_kernel<<<dim3(PTOT / 256, GB), 256, 0, stream>>>(p1, p2, p3, pooled, g0);
    assemble_kernel<<<dim3((HWo * KP1) / 256, GB), 256, 0, stream>>>(pooled, xcb);
    gemm1_mfma<<<dim3(GB * NP / 128, ODIM / 128), 256, 0, stream>>>(Wh, bias, xcb, phi_t);
    rownorm_kernel<<<GB * NP / 4, 256, 0, stream>>>(phi_t, feat);
    gemm2_mfma<<<dim3(NP / 128, GB * NP / 128), 256, 0, stream>>>(phi_t, Ct, cent, key);
    topk_kernel<<<GB * HWo / 4, 256, 0, stream>>>(key, feat, out, g0);
  }
}